// Round 3
// baseline (983.648 us; speedup 1.0000x reference)
//
#include <hip/hip_runtime.h>

#define N_EDGE 40000
#define BLOCKS 1250   // 1250 blocks x 4 waves x 8 edges = 40000

// ---------------- path table (compile-time, mirrors Python _PATHS order) ----
__device__ float g_cg[1875];

__device__ const int PL1[23] = {0,0,0,0, 1,1,1,1,1,1, 2,2,2,2,2,2,2, 3,3,3,3,3,3};
__device__ const int PL2[23] = {0,1,2,3, 0,1,1,2,2,3, 0,1,1,2,2,3,3, 0,1,2,2,3,3};
__device__ const int PL3[23] = {0,1,2,3, 1,0,2,1,3,2, 2,1,3,0,2,1,3, 3,2,1,3,0,2};
__device__ const int PCO[23] = {0,1,10,35, 84,93,102,147,192,297,
                                402,427,472,577,602,727,832,
                                1077,1126,1231,1336,1581,1630};

// ---------------- device CG math (mirrors the Python reference) -------------
__device__ inline double dfact(int n) {
    double r = 1.0;
    for (int i = 2; i <= n; ++i) r *= (double)i;
    return r;
}
__device__ inline int imax2(int a, int b) { return a > b ? a : b; }
__device__ inline int imin2(int a, int b) { return a < b ? a : b; }

__device__ double cg_coeff(int j1, int m1, int j2, int m2, int j3, int m3) {
    if (m3 != m1 + m2) return 0.0;
    int vmin = imax2(0, imax2(j2 - j3 - m1, j1 - j3 + m2));
    int vmax = imin2(j1 + j2 - j3, imin2(j1 - m1, j2 + m2));
    if (vmax < vmin) return 0.0;
    double pref = sqrt((double)(2 * j3 + 1) * dfact(j3 + j1 - j2) * dfact(j3 - j1 + j2) *
                       dfact(j1 + j2 - j3) / dfact(j1 + j2 + j3 + 1));
    pref *= sqrt(dfact(j3 + m3) * dfact(j3 - m3) * dfact(j1 - m1) * dfact(j1 + m1) *
                 dfact(j2 - m2) * dfact(j2 + m2));
    double s = 0.0;
    for (int v = vmin; v <= vmax; ++v) {
        double term = 1.0 / (dfact(v) * dfact(j1 + j2 - j3 - v) * dfact(j1 - m1 - v) *
                             dfact(j2 + m2 - v) * dfact(j3 - j2 + m1 + v) * dfact(j3 - j1 - m2 + v));
        s += (v & 1) ? -term : term;
    }
    return pref * s;
}

__device__ void make_q(int l, double* qre, double* qim) {
    int n = 2 * l + 1;
    for (int i = 0; i < n * n; ++i) { qre[i] = 0.0; qim[i] = 0.0; }
    const double s = 0.70710678118654752440;
    for (int m = -l; m < 0; ++m) {
        int am = -m;
        qre[(l + m) * n + (l + am)] = s;
        qim[(l + m) * n + (l - am)] = -s;
    }
    qre[l * n + l] = 1.0;
    for (int m = 1; m <= l; ++m) {
        double sgn = (m & 1) ? -1.0 : 1.0;
        qre[(l + m) * n + (l + m)] = sgn * s;
        qim[(l + m) * n + (l - m)] = sgn * s;
    }
    int ph = l & 3;
    if (ph) {
        for (int i = 0; i < n * n; ++i) {
            double re = qre[i], im = qim[i];
            if (ph == 1)      { qre[i] =  im; qim[i] = -re; }
            else if (ph == 2) { qre[i] = -re; qim[i] = -im; }
            else              { qre[i] = -im; qim[i] =  re; }
        }
    }
}

__global__ void cg_setup_kernel() {
    const int p  = blockIdx.x;
    const int l1 = PL1[p], l2 = PL2[p], l3 = PL3[p];
    const int n1 = 2 * l1 + 1, n2 = 2 * l2 + 1, n3 = 2 * l3 + 1;
    const int nD = n1 * n2 * n3;
    const int tid = threadIdx.x;

    __shared__ double cgc[343];
    __shared__ double q1re[49], q1im[49], q2re[49], q2im[49], q3re[49], q3im[49];
    __shared__ double red[256];

    for (int t = tid; t < nD; t += blockDim.x) {
        int a = t / (n2 * n3);
        int b = (t / n3) % n2;
        int cc = t % n3;
        cgc[t] = cg_coeff(l1, a - l1, l2, b - l2, l3, cc - l3);
    }
    if (tid == 0) {
        make_q(l1, q1re, q1im);
        make_q(l2, q2re, q2im);
        make_q(l3, q3re, q3im);
    }
    __syncthreads();

    double dre = 0.0, dim = 0.0;
    if (tid < nD) {
        const int i = tid / (n2 * n3);
        const int j = (tid / n3) % n2;
        const int k = tid % n3;
        for (int a = 0; a < n1; ++a) {
            double q1r = q1re[i * n1 + a], q1i = q1im[i * n1 + a];
            if (q1r == 0.0 && q1i == 0.0) continue;
            for (int b = 0; b < n2; ++b) {
                double q2r = q2re[j * n2 + b], q2i = q2im[j * n2 + b];
                if (q2r == 0.0 && q2i == 0.0) continue;
                double wr = q1r * q2r - q1i * q2i;
                double wi = q1r * q2i + q1i * q2r;
                for (int cc = 0; cc < n3; ++cc) {
                    double g = cgc[(a * n2 + b) * n3 + cc];
                    if (g == 0.0) continue;
                    double q3r = q3re[k * n3 + cc];
                    double q3i = -q3im[k * n3 + cc];  // conj
                    dre += (wr * q3r - wi * q3i) * g;
                    dim += (wr * q3i + wi * q3r) * g;
                }
            }
        }
    }

    red[tid] = (tid < nD) ? dre * dre : 0.0;
    __syncthreads();
    for (int s = 128; s > 0; s >>= 1) {
        if (tid < s) red[tid] += red[tid + s];
        __syncthreads();
    }
    double sum_re = red[0];
    __syncthreads();
    red[tid] = (tid < nD) ? dim * dim : 0.0;
    __syncthreads();
    for (int s = 128; s > 0; s >>= 1) {
        if (tid < s) red[tid] += red[tid + s];
        __syncthreads();
    }
    double sum_im = red[0];

    bool use_re = (sum_re >= sum_im);
    double nrm = sqrt(use_re ? sum_re : sum_im);
    if (tid < nD) {
        double v = (use_re ? dre : dim) / nrm;
        g_cg[PCO[p] + tid] = (float)v;
    }
}

// ---------------- main tensor-product kernel --------------------------------
template <int L1, int L2, int L3, int RO, int CO>
__device__ __forceinline__ void do_path2(const float* xv0, const float* xv1,
                                         const float* yv0, const float* yv1,
                                         const float* cg, float* o0, float* o1) {
    constexpr int N1 = 2 * L1 + 1, N2 = 2 * L2 + 1, N3 = 2 * L3 + 1;
    constexpr int X0 = L1 * L1, Y0 = L2 * L2;
    float a0[N3], a1[N3];
#pragma unroll
    for (int k = 0; k < N3; ++k) { a0[k] = 0.f; a1[k] = 0.f; }
#pragma unroll
    for (int i = 0; i < N1; ++i) {
#pragma unroll
        for (int j = 0; j < N2; ++j) {
            float t0 = xv0[X0 + i] * yv0[Y0 + j];
            float t1 = xv1[X0 + i] * yv1[Y0 + j];
#pragma unroll
            for (int k = 0; k < N3; ++k) {
                const int m1 = i - L1, m2 = j - L2, m3 = k - L3;
                const int am1 = m1 < 0 ? -m1 : m1;
                const int am2 = m2 < 0 ? -m2 : m2;
                const int am3 = m3 < 0 ? -m3 : m3;
                const int d = am1 - am2;
                const int ad = d < 0 ? -d : d;
                if (am3 == am1 + am2 || am3 == ad) {
                    float cgv = cg[CO + (i * N2 + j) * N3 + k];
                    a0[k] += cgv * t0;
                    a1[k] += cgv * t1;
                }
            }
        }
    }
#pragma unroll
    for (int k = 0; k < N3; ++k) {
        o0[(RO + k) * 64] = a0[k];
        o1[(RO + k) * 64] = a1[k];
    }
}

// issue x loads for an edge-pair into register buffers (fire-and-forget;
// the s_waitcnt is inserted by the compiler at first use in compute_pair)
__device__ __forceinline__ void load_pair(const float* __restrict__ x,
                                          int e0, int c,
                                          float* xv0, float* xv1) {
    const float* xp0 = x + (size_t)e0 * 1024 + c;
    const float* xp1 = xp0 + 1024;
#pragma unroll
    for (int i = 0; i < 16; ++i) { xv0[i] = xp0[i * 64]; xv1[i] = xp1[i * 64]; }
}

__device__ __forceinline__ void compute_pair(const float* __restrict__ y,
                                             float* __restrict__ out,
                                             const float* cg_s,
                                             int e0, int c,
                                             const float* xv0, const float* xv1) {
    // y is wave-uniform (e0 built from SGPRs) -> scalar loads
    const float* yp0 = y + (size_t)e0 * 16;
    float yv0[16], yv1[16];
#pragma unroll
    for (int j = 0; j < 16; ++j) { yv0[j] = yp0[j]; yv1[j] = yp0[16 + j]; }

    float* o0 = out + (size_t)e0 * 99 * 64 + c;
    float* o1 = o0 + 99 * 64;

    do_path2<0,0,0,  0,    0>(xv0, xv1, yv0, yv1, cg_s, o0, o1);
    do_path2<0,1,1,  1,    1>(xv0, xv1, yv0, yv1, cg_s, o0, o1);
    do_path2<0,2,2,  4,   10>(xv0, xv1, yv0, yv1, cg_s, o0, o1);
    do_path2<0,3,3,  9,   35>(xv0, xv1, yv0, yv1, cg_s, o0, o1);
    do_path2<1,0,1, 16,   84>(xv0, xv1, yv0, yv1, cg_s, o0, o1);
    do_path2<1,1,0, 19,   93>(xv0, xv1, yv0, yv1, cg_s, o0, o1);
    do_path2<1,1,2, 20,  102>(xv0, xv1, yv0, yv1, cg_s, o0, o1);
    do_path2<1,2,1, 25,  147>(xv0, xv1, yv0, yv1, cg_s, o0, o1);
    do_path2<1,2,3, 28,  192>(xv0, xv1, yv0, yv1, cg_s, o0, o1);
    do_path2<1,3,2, 35,  297>(xv0, xv1, yv0, yv1, cg_s, o0, o1);
    do_path2<2,0,2, 40,  402>(xv0, xv1, yv0, yv1, cg_s, o0, o1);
    do_path2<2,1,1, 45,  427>(xv0, xv1, yv0, yv1, cg_s, o0, o1);
    do_path2<2,1,3, 48,  472>(xv0, xv1, yv0, yv1, cg_s, o0, o1);
    do_path2<2,2,0, 55,  577>(xv0, xv1, yv0, yv1, cg_s, o0, o1);
    do_path2<2,2,2, 56,  602>(xv0, xv1, yv0, yv1, cg_s, o0, o1);
    do_path2<2,3,1, 61,  727>(xv0, xv1, yv0, yv1, cg_s, o0, o1);
    do_path2<2,3,3, 64,  832>(xv0, xv1, yv0, yv1, cg_s, o0, o1);
    do_path2<3,0,3, 71, 1077>(xv0, xv1, yv0, yv1, cg_s, o0, o1);
    do_path2<3,1,2, 78, 1126>(xv0, xv1, yv0, yv1, cg_s, o0, o1);
    do_path2<3,2,1, 83, 1231>(xv0, xv1, yv0, yv1, cg_s, o0, o1);
    do_path2<3,2,3, 86, 1336>(xv0, xv1, yv0, yv1, cg_s, o0, o1);
    do_path2<3,3,0, 93, 1581>(xv0, xv1, yv0, yv1, cg_s, o0, o1);
    do_path2<3,3,2, 94, 1630>(xv0, xv1, yv0, yv1, cg_s, o0, o1);
}

__global__ __launch_bounds__(256) void tp_main_kernel(const float* __restrict__ x,
                                                      const float* __restrict__ y,
                                                      float* __restrict__ out) {
    __shared__ float cg_s[1875];
    for (int t = threadIdx.x; t < 1875; t += 256) cg_s[t] = g_cg[t];
    __syncthreads();

    // wave-uniform edge base (SGPR arithmetic) so y loads scalarize
    const int wu = __builtin_amdgcn_readfirstlane(threadIdx.x >> 6);
    const int c  = threadIdx.x & 63;
    const int ebase = (blockIdx.x * 4 + wu) * 8;   // 8 contiguous edges per wave

    float xA0[16], xA1[16], xB0[16], xB1[16];

    // software pipeline: issue next pair's loads before computing current.
    // Buffer reuse (A,B alternation) creates anti-deps that keep VGPRs bounded.
    load_pair(x, ebase + 0, c, xA0, xA1);
    load_pair(x, ebase + 2, c, xB0, xB1);
    compute_pair(y, out, cg_s, ebase + 0, c, xA0, xA1);
    load_pair(x, ebase + 4, c, xA0, xA1);
    compute_pair(y, out, cg_s, ebase + 2, c, xB0, xB1);
    load_pair(x, ebase + 6, c, xB0, xB1);
    compute_pair(y, out, cg_s, ebase + 4, c, xA0, xA1);
    compute_pair(y, out, cg_s, ebase + 6, c, xB0, xB1);
}

// ---------------- launch ----------------------------------------------------
extern "C" void kernel_launch(void* const* d_in, const int* in_sizes, int n_in,
                              void* d_out, int out_size, void* d_ws, size_t ws_size,
                              hipStream_t stream) {
    const float* x = (const float*)d_in[0];
    const float* y = (const float*)d_in[1];
    float* out = (float*)d_out;

    cg_setup_kernel<<<dim3(23), dim3(256), 0, stream>>>();
    tp_main_kernel<<<dim3(BLOCKS), dim3(256), 0, stream>>>(x, y, out);
}

// Round 4
// 213.167 us; speedup vs baseline: 4.6144x; 4.6144x over previous
//
#include <hip/hip_runtime.h>

#define N_EDGE 40000

// ===================== compile-time CG machinery =============================
constexpr double csqrt(double x) {
    if (x <= 0.0) return 0.0;
    double g = x < 1.0 ? 1.0 : x;
    for (int i = 0; i < 40; ++i) g = 0.5 * (g + x / g);
    return g;
}
constexpr double dfact(int n) {
    double r = 1.0;
    for (int i = 2; i <= n; ++i) r *= (double)i;
    return r;
}
constexpr int cmax(int a, int b) { return a > b ? a : b; }
constexpr int cmin(int a, int b) { return a < b ? a : b; }

constexpr double cg_coeff(int j1, int m1, int j2, int m2, int j3, int m3) {
    if (m3 != m1 + m2) return 0.0;
    int vmin = cmax(0, cmax(j2 - j3 - m1, j1 - j3 + m2));
    int vmax = cmin(j1 + j2 - j3, cmin(j1 - m1, j2 + m2));
    if (vmax < vmin) return 0.0;
    double pref = csqrt((double)(2 * j3 + 1) * dfact(j3 + j1 - j2) * dfact(j3 - j1 + j2) *
                        dfact(j1 + j2 - j3) / dfact(j1 + j2 + j3 + 1));
    pref *= csqrt(dfact(j3 + m3) * dfact(j3 - m3) * dfact(j1 - m1) * dfact(j1 + m1) *
                  dfact(j2 - m2) * dfact(j2 + m2));
    double s = 0.0;
    for (int v = vmin; v <= vmax; ++v) {
        double term = 1.0 / (dfact(v) * dfact(j1 + j2 - j3 - v) * dfact(j1 - m1 - v) *
                             dfact(j2 + m2 - v) * dfact(j3 - j2 + m1 + v) * dfact(j3 - j1 - m2 + v));
        s += (v & 1) ? -term : term;
    }
    return pref * s;
}

constexpr void make_q(int l, double* qre, double* qim) {
    int n = 2 * l + 1;
    for (int i = 0; i < n * n; ++i) { qre[i] = 0.0; qim[i] = 0.0; }
    const double s = 0.70710678118654752440;
    for (int m = -l; m < 0; ++m) {
        int am = -m;
        qre[(l + m) * n + (l + am)] = s;
        qim[(l + m) * n + (l - am)] = -s;
    }
    qre[l * n + l] = 1.0;
    for (int m = 1; m <= l; ++m) {
        double sgn = (m & 1) ? -1.0 : 1.0;
        qre[(l + m) * n + (l + m)] = sgn * s;
        qim[(l + m) * n + (l - m)] = sgn * s;
    }
    int ph = l & 3;
    if (ph) {
        for (int i = 0; i < n * n; ++i) {
            double re = qre[i], im = qim[i];
            if (ph == 1)      { qre[i] =  im; qim[i] = -re; }
            else if (ph == 2) { qre[i] = -re; qim[i] = -im; }
            else              { qre[i] = -im; qim[i] =  re; }
        }
    }
}

template <int L1, int L2, int L3>
struct RealCG {
    static constexpr int N1 = 2 * L1 + 1, N2 = 2 * L2 + 1, N3 = 2 * L3 + 1;
    float v[N1 * N2 * N3];
    constexpr RealCG() : v{} {
        double cg[N1 * N2 * N3] = {};
        for (int i = 0; i < N1; ++i)
            for (int j = 0; j < N2; ++j) {
                int m1 = i - L1, m2 = j - L2, m3 = m1 + m2;
                if (m3 >= -L3 && m3 <= L3)
                    cg[(i * N2 + j) * N3 + (m3 + L3)] = cg_coeff(L1, m1, L2, m2, L3, m3);
            }
        double q1r[N1 * N1] = {}, q1i[N1 * N1] = {};
        double q2r[N2 * N2] = {}, q2i[N2 * N2] = {};
        double q3r[N3 * N3] = {}, q3i[N3 * N3] = {};
        make_q(L1, q1r, q1i);
        make_q(L2, q2r, q2i);
        make_q(L3, q3r, q3i);
        double dr[N1 * N2 * N3] = {}, di[N1 * N2 * N3] = {};
        for (int i = 0; i < N1; ++i)
            for (int j = 0; j < N2; ++j)
                for (int k = 0; k < N3; ++k) {
                    double accr = 0.0, acci = 0.0;
                    for (int a = 0; a < N1; ++a) {
                        double x1r = q1r[i * N1 + a], x1i = q1i[i * N1 + a];
                        if (x1r == 0.0 && x1i == 0.0) continue;
                        for (int b = 0; b < N2; ++b) {
                            double x2r = q2r[j * N2 + b], x2i = q2i[j * N2 + b];
                            if (x2r == 0.0 && x2i == 0.0) continue;
                            double wr = x1r * x2r - x1i * x2i;
                            double wi = x1r * x2i + x1i * x2r;
                            for (int cc = 0; cc < N3; ++cc) {
                                double g = cg[(a * N2 + b) * N3 + cc];
                                if (g == 0.0) continue;
                                double zr = q3r[k * N3 + cc];
                                double zi = -q3i[k * N3 + cc];  // conj
                                accr += (wr * zr - wi * zi) * g;
                                acci += (wr * zi + wi * zr) * g;
                            }
                        }
                    }
                    dr[(i * N2 + j) * N3 + k] = accr;
                    di[(i * N2 + j) * N3 + k] = acci;
                }
        double sr = 0.0, si = 0.0;
        for (int t = 0; t < N1 * N2 * N3; ++t) { sr += dr[t] * dr[t]; si += di[t] * di[t]; }
        bool use_re = (sr >= si);
        double nrm = csqrt(use_re ? sr : si);
        for (int t = 0; t < N1 * N2 * N3; ++t) {
            double val = (use_re ? dr[t] : di[t]) / nrm;
            if (val < 1e-7 && val > -1e-7) val = 0.0;  // drop cancellation residue
            v[t] = (float)val;
        }
    }
};

template <int L1, int L2, int L3>
inline constexpr RealCG<L1, L2, L3> g_rcg{};

// ===================== compile-time unroller =================================
template <int I> struct ic { static constexpr int value = I; };

template <int N, int I = 0, class F>
__device__ __forceinline__ void cunroll(F&& f) {
    if constexpr (I < N) {
        f(ic<I>{});
        cunroll<N, I + 1>(f);
    }
}

// ===================== main tensor-product kernel ============================
// All CG values are compile-time float literals; exact zeros pruned by
// `if constexpr` so no 0*t FMAs are emitted.
template <int L1, int L2, int L3, int RO>
__device__ __forceinline__ void do_path(const float* xv, const float* yv, float* o) {
    constexpr int N2 = 2 * L2 + 1, N3 = 2 * L3 + 1;
    constexpr int X0 = L1 * L1, Y0 = L2 * L2;
    float a[N3];
    cunroll<N3>([&](auto K) { a[K.value] = 0.f; });
    cunroll<2 * L1 + 1>([&](auto I) {
        cunroll<N2>([&](auto J) {
            float t = xv[X0 + I.value] * yv[Y0 + J.value];  // DCE'd if all k pruned
            cunroll<N3>([&](auto K) {
                constexpr float cgv =
                    g_rcg<L1, L2, L3>.v[(I.value * N2 + J.value) * N3 + K.value];
                if constexpr (cgv != 0.0f) a[K.value] += cgv * t;
            });
        });
    });
    cunroll<N3>([&](auto K) { o[(RO + K.value) * 64] = a[K.value]; });
}

__global__ __launch_bounds__(256) void tp_main_kernel(const float* __restrict__ x,
                                                      const float* __restrict__ y,
                                                      float* __restrict__ out) {
    const int c = threadIdx.x & 63;
    const int e = blockIdx.x * 4 + (threadIdx.x >> 6);  // 1 edge per wave

    const float* xp = x + (size_t)e * 1024 + c;
    float xv[16];
#pragma unroll
    for (int i = 0; i < 16; ++i) xv[i] = xp[i * 64];

    const float* yp = y + (size_t)e * 16;
    float yv[16];
#pragma unroll
    for (int j = 0; j < 16; ++j) yv[j] = yp[j];

    float* o = out + (size_t)e * 99 * 64 + c;

    do_path<0,0,0,  0>(xv, yv, o);
    do_path<0,1,1,  1>(xv, yv, o);
    do_path<0,2,2,  4>(xv, yv, o);
    do_path<0,3,3,  9>(xv, yv, o);
    do_path<1,0,1, 16>(xv, yv, o);
    do_path<1,1,0, 19>(xv, yv, o);
    do_path<1,1,2, 20>(xv, yv, o);
    do_path<1,2,1, 25>(xv, yv, o);
    do_path<1,2,3, 28>(xv, yv, o);
    do_path<1,3,2, 35>(xv, yv, o);
    do_path<2,0,2, 40>(xv, yv, o);
    do_path<2,1,1, 45>(xv, yv, o);
    do_path<2,1,3, 48>(xv, yv, o);
    do_path<2,2,0, 55>(xv, yv, o);
    do_path<2,2,2, 56>(xv, yv, o);
    do_path<2,3,1, 61>(xv, yv, o);
    do_path<2,3,3, 64>(xv, yv, o);
    do_path<3,0,3, 71>(xv, yv, o);
    do_path<3,1,2, 78>(xv, yv, o);
    do_path<3,2,1, 83>(xv, yv, o);
    do_path<3,2,3, 86>(xv, yv, o);
    do_path<3,3,0, 93>(xv, yv, o);
    do_path<3,3,2, 94>(xv, yv, o);
}

// ===================== launch ================================================
extern "C" void kernel_launch(void* const* d_in, const int* in_sizes, int n_in,
                              void* d_out, int out_size, void* d_ws, size_t ws_size,
                              hipStream_t stream) {
    const float* x = (const float*)d_in[0];
    const float* y = (const float*)d_in[1];
    float* out = (float*)d_out;

    // 10000 blocks x 4 waves x 1 edge = 40000 edges; single launch, no LDS,
    // CG baked as instruction-stream literals at compile time.
    tp_main_kernel<<<dim3(N_EDGE / 4), dim3(256), 0, stream>>>(x, y, out);
}

// Round 5
// 196.543 us; speedup vs baseline: 5.0048x; 1.0846x over previous
//
#include <hip/hip_runtime.h>

#define N_EDGE 40000

// ===================== compile-time CG machinery =============================
constexpr double csqrt(double x) {
    if (x <= 0.0) return 0.0;
    double g = x < 1.0 ? 1.0 : x;
    for (int i = 0; i < 40; ++i) g = 0.5 * (g + x / g);
    return g;
}
constexpr double dfact(int n) {
    double r = 1.0;
    for (int i = 2; i <= n; ++i) r *= (double)i;
    return r;
}
constexpr int cmax(int a, int b) { return a > b ? a : b; }
constexpr int cmin(int a, int b) { return a < b ? a : b; }

constexpr double cg_coeff(int j1, int m1, int j2, int m2, int j3, int m3) {
    if (m3 != m1 + m2) return 0.0;
    int vmin = cmax(0, cmax(j2 - j3 - m1, j1 - j3 + m2));
    int vmax = cmin(j1 + j2 - j3, cmin(j1 - m1, j2 + m2));
    if (vmax < vmin) return 0.0;
    double pref = csqrt((double)(2 * j3 + 1) * dfact(j3 + j1 - j2) * dfact(j3 - j1 + j2) *
                        dfact(j1 + j2 - j3) / dfact(j1 + j2 + j3 + 1));
    pref *= csqrt(dfact(j3 + m3) * dfact(j3 - m3) * dfact(j1 - m1) * dfact(j1 + m1) *
                  dfact(j2 - m2) * dfact(j2 + m2));
    double s = 0.0;
    for (int v = vmin; v <= vmax; ++v) {
        double term = 1.0 / (dfact(v) * dfact(j1 + j2 - j3 - v) * dfact(j1 - m1 - v) *
                             dfact(j2 + m2 - v) * dfact(j3 - j2 + m1 + v) * dfact(j3 - j1 - m2 + v));
        s += (v & 1) ? -term : term;
    }
    return pref * s;
}

constexpr void make_q(int l, double* qre, double* qim) {
    int n = 2 * l + 1;
    for (int i = 0; i < n * n; ++i) { qre[i] = 0.0; qim[i] = 0.0; }
    const double s = 0.70710678118654752440;
    for (int m = -l; m < 0; ++m) {
        int am = -m;
        qre[(l + m) * n + (l + am)] = s;
        qim[(l + m) * n + (l - am)] = -s;
    }
    qre[l * n + l] = 1.0;
    for (int m = 1; m <= l; ++m) {
        double sgn = (m & 1) ? -1.0 : 1.0;
        qre[(l + m) * n + (l + m)] = sgn * s;
        qim[(l + m) * n + (l - m)] = sgn * s;
    }
    int ph = l & 3;
    if (ph) {
        for (int i = 0; i < n * n; ++i) {
            double re = qre[i], im = qim[i];
            if (ph == 1)      { qre[i] =  im; qim[i] = -re; }
            else if (ph == 2) { qre[i] = -re; qim[i] = -im; }
            else              { qre[i] = -im; qim[i] =  re; }
        }
    }
}

template <int L1, int L2, int L3>
struct RealCG {
    static constexpr int N1 = 2 * L1 + 1, N2 = 2 * L2 + 1, N3 = 2 * L3 + 1;
    float v[N1 * N2 * N3];
    constexpr RealCG() : v{} {
        double cg[N1 * N2 * N3] = {};
        for (int i = 0; i < N1; ++i)
            for (int j = 0; j < N2; ++j) {
                int m1 = i - L1, m2 = j - L2, m3 = m1 + m2;
                if (m3 >= -L3 && m3 <= L3)
                    cg[(i * N2 + j) * N3 + (m3 + L3)] = cg_coeff(L1, m1, L2, m2, L3, m3);
            }
        double q1r[N1 * N1] = {}, q1i[N1 * N1] = {};
        double q2r[N2 * N2] = {}, q2i[N2 * N2] = {};
        double q3r[N3 * N3] = {}, q3i[N3 * N3] = {};
        make_q(L1, q1r, q1i);
        make_q(L2, q2r, q2i);
        make_q(L3, q3r, q3i);
        double dr[N1 * N2 * N3] = {}, di[N1 * N2 * N3] = {};
        for (int i = 0; i < N1; ++i)
            for (int j = 0; j < N2; ++j)
                for (int k = 0; k < N3; ++k) {
                    double accr = 0.0, acci = 0.0;
                    for (int a = 0; a < N1; ++a) {
                        double x1r = q1r[i * N1 + a], x1i = q1i[i * N1 + a];
                        if (x1r == 0.0 && x1i == 0.0) continue;
                        for (int b = 0; b < N2; ++b) {
                            double x2r = q2r[j * N2 + b], x2i = q2i[j * N2 + b];
                            if (x2r == 0.0 && x2i == 0.0) continue;
                            double wr = x1r * x2r - x1i * x2i;
                            double wi = x1r * x2i + x1i * x2r;
                            for (int cc = 0; cc < N3; ++cc) {
                                double g = cg[(a * N2 + b) * N3 + cc];
                                if (g == 0.0) continue;
                                double zr = q3r[k * N3 + cc];
                                double zi = -q3i[k * N3 + cc];  // conj
                                accr += (wr * zr - wi * zi) * g;
                                acci += (wr * zi + wi * zr) * g;
                            }
                        }
                    }
                    dr[(i * N2 + j) * N3 + k] = accr;
                    di[(i * N2 + j) * N3 + k] = acci;
                }
        double sr = 0.0, si = 0.0;
        for (int t = 0; t < N1 * N2 * N3; ++t) { sr += dr[t] * dr[t]; si += di[t] * di[t]; }
        bool use_re = (sr >= si);
        double nrm = csqrt(use_re ? sr : si);
        for (int t = 0; t < N1 * N2 * N3; ++t) {
            double val = (use_re ? dr[t] : di[t]) / nrm;
            if (val < 1e-7 && val > -1e-7) val = 0.0;  // drop cancellation residue
            v[t] = (float)val;
        }
    }
};

template <int L1, int L2, int L3>
inline constexpr RealCG<L1, L2, L3> g_rcg{};

// ===================== compile-time unroller =================================
template <int I> struct ic { static constexpr int value = I; };

template <int N, int I = 0, class F>
__device__ __forceinline__ void cunroll(F&& f) {
    if constexpr (I < N) {
        f(ic<I>{});
        cunroll<N, I + 1>(f);
    }
}

// ===================== main tensor-product kernel ============================
// All CG values are compile-time float literals; exact zeros pruned by
// `if constexpr`. Output stores are NONTEMPORAL: out (1.01 GB, never re-read)
// must not evict x (164 MB) from the 256 MB L3 — x then stays L3-resident
// across graph replays.
template <int L1, int L2, int L3, int RO>
__device__ __forceinline__ void do_path(const float* xv, const float* yv, float* o) {
    constexpr int N2 = 2 * L2 + 1, N3 = 2 * L3 + 1;
    constexpr int X0 = L1 * L1, Y0 = L2 * L2;
    float a[N3];
    cunroll<N3>([&](auto K) { a[K.value] = 0.f; });
    cunroll<2 * L1 + 1>([&](auto I) {
        cunroll<N2>([&](auto J) {
            float t = xv[X0 + I.value] * yv[Y0 + J.value];  // DCE'd if all k pruned
            cunroll<N3>([&](auto K) {
                constexpr float cgv =
                    g_rcg<L1, L2, L3>.v[(I.value * N2 + J.value) * N3 + K.value];
                if constexpr (cgv != 0.0f) a[K.value] += cgv * t;
            });
        });
    });
    cunroll<N3>([&](auto K) {
        __builtin_nontemporal_store(a[K.value], o + (RO + K.value) * 64);
    });
}

__global__ __launch_bounds__(256) void tp_main_kernel(const float* __restrict__ x,
                                                      const float* __restrict__ y,
                                                      float* __restrict__ out) {
    const int c = threadIdx.x & 63;
    const int e = blockIdx.x * 4 + (threadIdx.x >> 6);  // 1 edge per wave

    const float* xp = x + (size_t)e * 1024 + c;
    float xv[16];
#pragma unroll
    for (int i = 0; i < 16; ++i) xv[i] = xp[i * 64];   // regular loads: keep x cached

    const float* yp = y + (size_t)e * 16;
    float yv[16];
#pragma unroll
    for (int j = 0; j < 16; ++j) yv[j] = yp[j];

    float* o = out + (size_t)e * 99 * 64 + c;

    do_path<0,0,0,  0>(xv, yv, o);
    do_path<0,1,1,  1>(xv, yv, o);
    do_path<0,2,2,  4>(xv, yv, o);
    do_path<0,3,3,  9>(xv, yv, o);
    do_path<1,0,1, 16>(xv, yv, o);
    do_path<1,1,0, 19>(xv, yv, o);
    do_path<1,1,2, 20>(xv, yv, o);
    do_path<1,2,1, 25>(xv, yv, o);
    do_path<1,2,3, 28>(xv, yv, o);
    do_path<1,3,2, 35>(xv, yv, o);
    do_path<2,0,2, 40>(xv, yv, o);
    do_path<2,1,1, 45>(xv, yv, o);
    do_path<2,1,3, 48>(xv, yv, o);
    do_path<2,2,0, 55>(xv, yv, o);
    do_path<2,2,2, 56>(xv, yv, o);
    do_path<2,3,1, 61>(xv, yv, o);
    do_path<2,3,3, 64>(xv, yv, o);
    do_path<3,0,3, 71>(xv, yv, o);
    do_path<3,1,2, 78>(xv, yv, o);
    do_path<3,2,1, 83>(xv, yv, o);
    do_path<3,2,3, 86>(xv, yv, o);
    do_path<3,3,0, 93>(xv, yv, o);
    do_path<3,3,2, 94>(xv, yv, o);
}

// ===================== launch ================================================
extern "C" void kernel_launch(void* const* d_in, const int* in_sizes, int n_in,
                              void* d_out, int out_size, void* d_ws, size_t ws_size,
                              hipStream_t stream) {
    const float* x = (const float*)d_in[0];
    const float* y = (const float*)d_in[1];
    float* out = (float*)d_out;

    // 10000 blocks x 4 waves x 1 edge = 40000 edges; single launch, no LDS,
    // CG baked as instruction-stream literals at compile time.
    tp_main_kernel<<<dim3(N_EDGE / 4), dim3(256), 0, stream>>>(x, y, out);
}